// Round 1
// 306.425 us; speedup vs baseline: 1.0679x; 1.0679x over previous
//
#include <hip/hip_runtime.h>
#include <math.h>

// ---------------------------------------------------------------------------
// AttentionNet weighted-anchor aggregator.
//   x:  (8, 448, 448, 3) f32
//   wp3:(8, 6, 4, 14, 14) f32   wp4:(8, 6, 4, 7, 7) f32   wp5:(8, 9, 4, 4, 4) f32
//   out:(32, 224, 224, 3) f32 = sum over 21 configs of
//        resize_bilinear( einsum('bkij,bihjwc->bkhwc', w, patches), 224,224 )
//
// Phase 0a: init_tables — normalized zero-padded 4-tap weights + i0.
// Phase 0b: transpose_w — weights to [cfg][b][grid][k0..k3] float4.
// Phase A : agg_all — ONE dispatch, block-uniform layer switch into templated
//           <GH,GW,STRIDE> bodies. BRANCH-FREE inner loop: per (i,j) two
//           clamped 12B dwordx3 loads (always issued -> batched by the
//           scheduler) + cndmask masking of out-of-image pixels. Row validity
//           stays in the i-loop bounds (free). bf16x4 (8 B/px) out.
// Phase B : resize_kernel — BARRIER-FREE direct-global gather. One px/thread,
//           z = 32 bk. Tap windows are ~5KB/block and L1/L2-resident, so LDS
//           staging + 21x2 barriers were pure overhead; each thread issues its
//           <=16 tap loads (b64) up-front for max MLP. Only the small weight
//           tables are staged in LDS once (one barrier total).
// ---------------------------------------------------------------------------

#define BATCH 8
#define KK 4
#define OUT_HW 224
#define IMG_HW 448
#define NCFG 21

#define WTBL_BYTES (NCFG * 2 * OUT_HW * 16)     // 150528
#define ITBL_BYTES (NCFG * 2 * OUT_HW * 4)      // 37632
#define WT_OFF_BYTES (WTBL_BYTES + ITBL_BYTES)  // 188160
#define WT_F4 12912                             // 8 * (6*196 + 6*49 + 9*16)
#define AGG_OFF_BYTES (WT_OFF_BYTES + WT_F4 * 16)  // 394752 (16B aligned)

struct CfgEntry {          // resize view of a config
    int kh, kw;
    int mth, mtw;          // max tap count per dim (2..4)
    int tbl;               // global cfg index (table lookup)
    int ws_off;            // px (uint2) offset in agg region
};

struct GroupArgs {
    CfgEntry e[NCFG];
    int n;
};

struct ACfg {              // agg view of a config
    int kh, kw, p0, p1;
    int layer;             // 0=p3, 1=p4, 2=p5
    int qpr;               // pairs (2px) per row = ceil(kw/2)
    int wt_off;            // float4 offset of transposed weights
    int ws_off;            // px offset in agg region
    int block_start;
    int blocks_per_img;    // ceil(kh*qpr/256)
};

struct AggArgs {
    ACfg e[NCFG];
    int n;
};

struct TablesArgs { int kh[NCFG]; int kw[NCFG]; };

struct TrArgs {
    int layer[NCFG];
    int anchor[NCFG];
    int gsz[NCFG];
    int wt_off[NCFG];
};

struct F3 { float a, b, c; };

__device__ inline unsigned int bf16_rne(float f) {
    unsigned int u = __float_as_uint(f);
    return (u + 0x7fffu + ((u >> 16) & 1u)) >> 16;
}

// ---------------------------------------------------------------------------
// Phase 0a: tap tables. jax.image.resize('bilinear', antialias=True):
//   inv=in/out; ks=max(inv,1); sf=(o+0.5)*inv-0.5; taps i in
//   [ceil(sf-ks), floor(sf+ks)] clamped, w=max(0,1-|i-sf|/ks) normalized.
// ---------------------------------------------------------------------------
__global__ __launch_bounds__(256) void init_tables(float4* __restrict__ wtbl,
                                                   int* __restrict__ itbl,
                                                   TablesArgs t) {
    int cfg = blockIdx.x >> 1;
    int dim = blockIdx.x & 1;
    int o = threadIdx.x;
    if (o >= OUT_HW) return;
    int n = dim ? t.kw[cfg] : t.kh[cfg];

    float inv = (float)(1.0 / ((double)OUT_HW / (double)n));
    float ks  = inv > 1.f ? inv : 1.f;
    float rks = 1.f / ks;
    float sf  = ((float)o + 0.5f) * inv - 0.5f;
    int i0 = (int)ceilf(sf - ks);  if (i0 < 0) i0 = 0;
    int i1 = (int)floorf(sf + ks); if (i1 > n - 1) i1 = n - 1;
    float sum = 0.f;
    for (int i = i0; i <= i1; ++i) {
        float v = 1.f - fabsf((float)i - sf) * rks;
        sum += (v > 0.f ? v : 0.f);
    }
    float rsum = 1.f / sum;
    float w[4];
#pragma unroll
    for (int d = 0; d < 4; ++d) {
        int i = i0 + d;
        float v = 0.f;
        if (i <= i1) {
            v = 1.f - fabsf((float)i - sf) * rks;
            v = (v > 0.f ? v : 0.f) * rsum;
        }
        w[d] = v;
    }
    int idx = cfg * (2 * OUT_HW) + dim * OUT_HW + o;
    wtbl[idx] = make_float4(w[0], w[1], w[2], w[3]);
    itbl[idx] = i0;
}

// ---------------------------------------------------------------------------
// Phase 0b: transpose weights (B,A,K,gh,gw) -> per cfg [b][g][k0..k3] float4.
// ---------------------------------------------------------------------------
__global__ __launch_bounds__(256) void transpose_w(
        const float* __restrict__ wp3, const float* __restrict__ wp4,
        const float* __restrict__ wp5, float4* __restrict__ wT, TrArgs t) {
    int cfg = blockIdx.x;
    int b = blockIdx.y;
    int gsz = t.gsz[cfg];
    const float* base;
    int A;
    if (t.layer[cfg] == 0)      { base = wp3; A = 6; }
    else if (t.layer[cfg] == 1) { base = wp4; A = 6; }
    else                        { base = wp5; A = 9; }
    const float* src = base + (size_t)(b * A + t.anchor[cfg]) * (KK * gsz);
    for (int g = threadIdx.x; g < gsz; g += 256) {
        wT[t.wt_off[cfg] + b * gsz + g] =
            make_float4(src[0 * gsz + g], src[1 * gsz + g],
                        src[2 * gsz + g], src[3 * gsz + g]);
    }
}

// ---------------------------------------------------------------------------
// Agg body (templated): 2 consecutive px per thread, acc[2][4][3].
// Branch-free: clamped dwordx3 loads always issue; invalid px zeroed by
// cndmask. Row validity handled by the i-loop bounds (no per-iter cost).
// ---------------------------------------------------------------------------
template <int GH, int GW, int STRIDE>
__device__ inline void agg_body(const ACfg& c, int b, int h, int w0,
                                const float* __restrict__ xb,
                                const float4* __restrict__ wlds,
                                uint2* __restrict__ agg) {
    float acc[2][4][3] = {};

    const int rb = h - c.p0;
    // valid i range: 0 <= rb + i*STRIDE <= IMG_HW-1
    int ilo = rb >= 0 ? 0 : (-rb + STRIDE - 1) / STRIDE;
    int ihi = (IMG_HW - 1 - rb) / STRIDE;
    if (ihi > GH - 1) ihi = GH - 1;

    const int cb = w0 - c.p1;

#pragma unroll 1
    for (int i = ilo; i <= ihi; ++i) {
        const float* xr = xb + (size_t)(rb + i * STRIDE) * (IMG_HW * 3);
        const float4* wrow = wlds + i * GW;
#pragma unroll
        for (int j = 0; j < GW; ++j) {
            int col = cb + j * STRIDE;
            int cc0 = col;
            if (cc0 < 0) cc0 = 0;
            if (cc0 > IMG_HW - 1) cc0 = IMG_HW - 1;
            int cc1 = col + 1;
            if (cc1 < 0) cc1 = 0;
            if (cc1 > IMG_HW - 1) cc1 = IMG_HW - 1;
            F3 v0 = *(const F3*)(xr + (size_t)cc0 * 3);
            F3 v1 = *(const F3*)(xr + (size_t)cc1 * 3);
            bool k0 = (unsigned)col < (unsigned)IMG_HW;
            bool k1 = (unsigned)(col + 1) < (unsigned)IMG_HW;
            float x0 = k0 ? v0.a : 0.f;
            float x1 = k0 ? v0.b : 0.f;
            float x2 = k0 ? v0.c : 0.f;
            float y0 = k1 ? v1.a : 0.f;
            float y1 = k1 ? v1.b : 0.f;
            float y2 = k1 ? v1.c : 0.f;
            float4 wk = wrow[j];   // uniform address -> broadcast b128
            acc[0][0][0] = fmaf(wk.x, x0, acc[0][0][0]);
            acc[0][0][1] = fmaf(wk.x, x1, acc[0][0][1]);
            acc[0][0][2] = fmaf(wk.x, x2, acc[0][0][2]);
            acc[0][1][0] = fmaf(wk.y, x0, acc[0][1][0]);
            acc[0][1][1] = fmaf(wk.y, x1, acc[0][1][1]);
            acc[0][1][2] = fmaf(wk.y, x2, acc[0][1][2]);
            acc[0][2][0] = fmaf(wk.z, x0, acc[0][2][0]);
            acc[0][2][1] = fmaf(wk.z, x1, acc[0][2][1]);
            acc[0][2][2] = fmaf(wk.z, x2, acc[0][2][2]);
            acc[0][3][0] = fmaf(wk.w, x0, acc[0][3][0]);
            acc[0][3][1] = fmaf(wk.w, x1, acc[0][3][1]);
            acc[0][3][2] = fmaf(wk.w, x2, acc[0][3][2]);
            acc[1][0][0] = fmaf(wk.x, y0, acc[1][0][0]);
            acc[1][0][1] = fmaf(wk.x, y1, acc[1][0][1]);
            acc[1][0][2] = fmaf(wk.x, y2, acc[1][0][2]);
            acc[1][1][0] = fmaf(wk.y, y0, acc[1][1][0]);
            acc[1][1][1] = fmaf(wk.y, y1, acc[1][1][1]);
            acc[1][1][2] = fmaf(wk.y, y2, acc[1][1][2]);
            acc[1][2][0] = fmaf(wk.z, y0, acc[1][2][0]);
            acc[1][2][1] = fmaf(wk.z, y1, acc[1][2][1]);
            acc[1][2][2] = fmaf(wk.z, y2, acc[1][2][2]);
            acc[1][3][0] = fmaf(wk.w, y0, acc[1][3][0]);
            acc[1][3][1] = fmaf(wk.w, y1, acc[1][3][1]);
            acc[1][3][2] = fmaf(wk.w, y2, acc[1][3][2]);
        }
    }

    const int npix = c.kh * c.kw;
    const bool two = (w0 + 1) < c.kw;
#pragma unroll
    for (int k = 0; k < 4; ++k) {
        size_t base = (size_t)c.ws_off + (size_t)(b * KK + k) * npix
                    + (size_t)h * c.kw + w0;
        uint2 o0;
        o0.x = bf16_rne(acc[0][k][0]) | (bf16_rne(acc[0][k][1]) << 16);
        o0.y = bf16_rne(acc[0][k][2]);
        agg[base] = o0;
        if (two) {
            uint2 o1;
            o1.x = bf16_rne(acc[1][k][0]) | (bf16_rne(acc[1][k][1]) << 16);
            o1.y = bf16_rne(acc[1][k][2]);
            agg[base + 1] = o1;
        }
    }
}

// ---------------------------------------------------------------------------
// Phase A: one dispatch for all configs; block-uniform layer switch.
// ---------------------------------------------------------------------------
__global__ __launch_bounds__(256, 4) void agg_all(
        const float* __restrict__ x,
        const float4* __restrict__ wT,
        uint2* __restrict__ agg,
        AggArgs a) {
    int bid = blockIdx.x;
    int ci = 0;
    while (ci + 1 < a.n && bid >= a.e[ci + 1].block_start) ci++;
    const ACfg c = a.e[ci];
    int local = bid - c.block_start;
    int b     = local / c.blocks_per_img;
    int sblk  = local - b * c.blocks_per_img;

    const int gsz = (c.layer == 0) ? 196 : (c.layer == 1) ? 49 : 16;
    __shared__ float4 wlds[196];
    for (int t = threadIdx.x; t < gsz; t += 256)
        wlds[t] = wT[c.wt_off + b * gsz + t];
    __syncthreads();

    int pidx = sblk * 256 + (int)threadIdx.x;
    if (pidx >= c.kh * c.qpr) return;
    int h  = pidx / c.qpr;
    int w0 = (pidx - h * c.qpr) * 2;

    const float* __restrict__ xb = x + (size_t)b * (IMG_HW * IMG_HW * 3);
    if (c.layer == 0)      agg_body<14, 14, 32>(c, b, h, w0, xb, wlds, agg);
    else if (c.layer == 1) agg_body<7, 7, 64>(c, b, h, w0, xb, wlds, agg);
    else                   agg_body<4, 4, 128>(c, b, h, w0, xb, wlds, agg);
}

// ---------------------------------------------------------------------------
// Tap micro-kernel: TH x TW taps gathered DIRECTLY from global agg (bf16x3
// uint2 px). All loads issued up-front (v[][] in registers) for max MLP.
// Out-of-range taps carry weight 0 in the tables; addresses are clamped.
// ---------------------------------------------------------------------------
template <int TH, int TW>
__device__ inline void taps_direct(const uint2* __restrict__ base,
                                   int kh, int kw, int i0, int j0,
                                   float4 wh4, float4 ww4,
                                   float& a0, float& a1, float& a2) {
    const float* wh = (const float*)&wh4;
    const float* ww = (const float*)&ww4;
    uint2 v[TH][TW];
#pragma unroll
    for (int d = 0; d < TH; ++d) {
        int gi = i0 + d;
        if (gi > kh - 1) gi = kh - 1;
        const uint2* rp = base + (size_t)gi * kw;
#pragma unroll
        for (int e = 0; e < TW; ++e) {
            int gj = j0 + e;
            if (gj > kw - 1) gj = kw - 1;
            v[d][e] = rp[gj];
        }
    }
#pragma unroll
    for (int d = 0; d < TH; ++d) {
        float r0 = 0.f, r1 = 0.f, r2 = 0.f;
#pragma unroll
        for (int e = 0; e < TW; ++e) {
            uint2 t = v[d][e];
            float c0 = __uint_as_float(t.x << 16);
            float c1 = __uint_as_float(t.x & 0xffff0000u);
            float c2 = __uint_as_float(t.y << 16);
            float w = ww[e];
            r0 = fmaf(w, c0, r0);
            r1 = fmaf(w, c1, r1);
            r2 = fmaf(w, c2, r2);
        }
        a0 = fmaf(wh[d], r0, a0);
        a1 = fmaf(wh[d], r1, a1);
        a2 = fmaf(wh[d], r2, a2);
    }
}

// ---------------------------------------------------------------------------
// Phase B: barrier-free resize. One output px per thread, z = bk (32).
// Weight tables staged to LDS once (single barrier); tap data gathered
// directly from global (L1/L2-resident windows), 21 rounds accumulated in
// registers.
// ---------------------------------------------------------------------------
__global__ __launch_bounds__(256) void resize_kernel(
        const uint2* __restrict__ agg,
        const float4* __restrict__ wtbl,
        const int* __restrict__ itbl,
        float* __restrict__ out,
        GroupArgs g, int accumulate) {
    const int tid = threadIdx.x;
    const int tx = tid & 15;
    const int ty = tid >> 4;
    const int xo = blockIdx.x * 16 + tx;
    const int yo = blockIdx.y * 16 + ty;
    const int bk = blockIdx.z;

    __shared__ float4 wlds[NCFG * 32];
    __shared__ int    ilds[NCFG * 32];

    const int nent = g.n * 32;
    for (int e = tid; e < nent; e += 256) {
        int ci  = e >> 5;
        int r   = e & 31;
        int isW = r >> 4;
        int idx = r & 15;
        int base_o = isW ? (blockIdx.x * 16) : (blockIdx.y * 16);
        int src = g.e[ci].tbl * (2 * OUT_HW) + isW * OUT_HW + base_o + idx;
        wlds[ci * 32 + r] = wtbl[src];
        ilds[ci * 32 + r] = itbl[src];
    }
    __syncthreads();

    size_t ob = (((size_t)bk * OUT_HW + yo) * OUT_HW + xo) * 3;
    float a0, a1, a2;
    if (accumulate) {
        a0 = out[ob]; a1 = out[ob + 1]; a2 = out[ob + 2];
    } else {
        a0 = a1 = a2 = 0.f;
    }

    for (int c = 0; c < g.n; ++c) {
        const CfgEntry e = g.e[c];
        float4 wh4 = wlds[c * 32 + ty];
        float4 ww4 = wlds[c * 32 + 16 + tx];
        int i0 = ilds[c * 32 + ty];
        int j0 = ilds[c * 32 + 16 + tx];
        const uint2* base = agg + (size_t)e.ws_off
                          + (size_t)bk * ((size_t)e.kh * e.kw);

        switch ((e.mth << 2) | e.mtw) {
            case (2 << 2) | 2:
                taps_direct<2, 2>(base, e.kh, e.kw, i0, j0, wh4, ww4, a0, a1, a2);
                break;
            case (3 << 2) | 2:
                taps_direct<3, 2>(base, e.kh, e.kw, i0, j0, wh4, ww4, a0, a1, a2);
                break;
            case (2 << 2) | 3:
                taps_direct<2, 3>(base, e.kh, e.kw, i0, j0, wh4, ww4, a0, a1, a2);
                break;
            case (3 << 2) | 3:
                taps_direct<3, 3>(base, e.kh, e.kw, i0, j0, wh4, ww4, a0, a1, a2);
                break;
            case (4 << 2) | 3:
                taps_direct<4, 3>(base, e.kh, e.kw, i0, j0, wh4, ww4, a0, a1, a2);
                break;
            case (3 << 2) | 4:
                taps_direct<3, 4>(base, e.kh, e.kw, i0, j0, wh4, ww4, a0, a1, a2);
                break;
            default:
                taps_direct<4, 4>(base, e.kh, e.kw, i0, j0, wh4, ww4, a0, a1, a2);
                break;
        }
    }

    out[ob + 0] = a0; out[ob + 1] = a1; out[ob + 2] = a2;
}

// ---------------------------------------------------------------------------
// Host launch
// ---------------------------------------------------------------------------
extern "C" void kernel_launch(void* const* d_in, const int* in_sizes, int n_in,
                              void* d_out, int out_size, void* d_ws, size_t ws_size,
                              hipStream_t stream) {
    const float* x   = (const float*)d_in[0];
    const float* wp3 = (const float*)d_in[1];
    const float* wp4 = (const float*)d_in[2];
    const float* wp5 = (const float*)d_in[3];
    float* out = (float*)d_out;
    float4* wtbl = (float4*)d_ws;
    int*    itbl = (int*)((char*)d_ws + WTBL_BYTES);
    float4* wT   = (float4*)((char*)d_ws + WT_OFF_BYTES);
    uint2*  agg  = (uint2*)((char*)d_ws + AGG_OFF_BYTES);

    // Build the 21 configs exactly as the reference does (double precision).
    struct { int stride, size, nscale; double scales[3]; int gh; } layers[3] = {
        {32, 48, 2, {pow(2.0, 1.0 / 3.0), pow(2.0, 2.0 / 3.0), 0.0}, 14},
        {64, 96, 2, {pow(2.0, 1.0 / 3.0), pow(2.0, 2.0 / 3.0), 0.0}, 7},
        {128, 192, 3, {1.0, pow(2.0, 1.0 / 3.0), pow(2.0, 2.0 / 3.0)}, 4},
    };
    const double ars[3] = {0.667, 1.0, 1.5};

    struct HostCfg {
        int kh, kw, stride, p0, p1, gh, gw, layer, anchor, mth, mtw, wt_off;
        int qpr, blocks_per_img;
    } cfg[NCFG];
    TablesArgs ta;
    TrArgs tr;
    int nc = 0, wt_run = 0;
    for (int L = 0; L < 3; ++L) {
        int anchor = 0;
        for (int si = 0; si < layers[L].nscale; ++si) {
            for (int ai = 0; ai < 3; ++ai) {
                double ss = (double)layers[L].size * layers[L].scales[si];
                double sq = pow(ars[ai], 0.5);
                int kh = (int)(ss / sq);
                int kw = (int)(ss * sq);
                HostCfg& e = cfg[nc];
                e.kh = kh; e.kw = kw;
                e.stride = layers[L].stride;
                e.p0 = (int)ceil((double)(kh - layers[L].stride) / 2.0);
                e.p1 = (int)ceil((double)(kw - layers[L].stride) / 2.0);
                e.gh = layers[L].gh; e.gw = layers[L].gh;
                e.layer = L; e.anchor = anchor++;
                e.mth = (kh < OUT_HW) ? 2 : (int)((2.0 * kh) / OUT_HW) + 1;
                e.mtw = (kw < OUT_HW) ? 2 : (int)((2.0 * kw) / OUT_HW) + 1;
                if (e.mth > 4) e.mth = 4;
                if (e.mtw > 4) e.mtw = 4;
                e.qpr = (kw + 1) / 2;
                e.blocks_per_img = (kh * e.qpr + 255) / 256;
                e.wt_off = wt_run;
                int gsz = e.gh * e.gw;
                wt_run += BATCH * gsz;
                ta.kh[nc] = kh; ta.kw[nc] = kw;
                tr.layer[nc] = L; tr.anchor[nc] = e.anchor;
                tr.gsz[nc] = gsz; tr.wt_off[nc] = e.wt_off;
                ++nc;
            }
        }
    }

    init_tables<<<NCFG * 2, 256, 0, stream>>>(wtbl, itbl, ta);
    transpose_w<<<dim3(NCFG, BATCH), 256, 0, stream>>>(wp3, wp4, wp5, wT, tr);

    size_t cap_px = (ws_size - AGG_OFF_BYTES) / 8;
    dim3 rgrid(OUT_HW / 16, OUT_HW / 16, BATCH * KK);

    int i = 0;
    int first = 1;
    while (i < NCFG) {
        // build a group
        int gstart = i;
        size_t used = 0;
        while (i < NCFG) {
            size_t need = (size_t)cfg[i].kh * cfg[i].kw * (BATCH * KK);
            if (i > gstart && used + need > cap_px) break;
            used += need;
            ++i;
            if (used >= cap_px) break;
        }
        GroupArgs g; g.n = 0;
        AggArgs aa; aa.n = 0;
        int ablocks = 0;
        size_t off = 0;
        for (int c = gstart; c < i; ++c) {
            ACfg& lc = aa.e[aa.n++];
            lc.kh = cfg[c].kh; lc.kw = cfg[c].kw;
            lc.p0 = cfg[c].p0; lc.p1 = cfg[c].p1;
            lc.layer = cfg[c].layer;
            lc.qpr = cfg[c].qpr;
            lc.wt_off = cfg[c].wt_off;
            lc.ws_off = (int)off;
            lc.block_start = ablocks;
            lc.blocks_per_img = cfg[c].blocks_per_img;
            ablocks += cfg[c].blocks_per_img * BATCH;
            CfgEntry& re = g.e[g.n++];
            re.kh = cfg[c].kh; re.kw = cfg[c].kw;
            re.mth = cfg[c].mth; re.mtw = cfg[c].mtw;
            re.tbl = c; re.ws_off = (int)off;
            off += (size_t)cfg[c].kh * cfg[c].kw * (BATCH * KK);
        }
        agg_all<<<ablocks, 256, 0, stream>>>(x, wT, agg, aa);
        resize_kernel<<<rgrid, 256, 0, stream>>>(agg, wtbl, itbl, out, g, first ? 0 : 1);
        first = 0;
    }
    (void)in_sizes; (void)n_in; (void)out_size;
}